// Round 11
// baseline (144.835 us; speedup 1.0000x reference)
//
#include <hip/hip_runtime.h>
#include <hip/hip_bf16.h>

typedef _Float16 f16_t;
typedef __attribute__((ext_vector_type(8))) _Float16 f16x8;
typedef __attribute__((ext_vector_type(4))) float f32x4;

// compiler memory-ordering fence (no instructions emitted)
#define LFENCE() asm volatile("" ::: "memory")

__device__ __forceinline__ f16x8 cvt8(const float* p) {
  float4 v0 = *(const float4*)p;
  float4 v1 = *(const float4*)(p + 4);
  f16x8 a;
  a[0] = (f16_t)v0.x; a[1] = (f16_t)v0.y; a[2] = (f16_t)v0.z; a[3] = (f16_t)v0.w;
  a[4] = (f16_t)v1.x; a[5] = (f16_t)v1.y; a[6] = (f16_t)v1.z; a[7] = (f16_t)v1.w;
  return a;
}

// ---------------------------------------------------------------------------
// prep (verified rounds 6-8): blocks 0..10 transpose+f16 weights
//   slots 0..7 = {wq_s,wk_s,wv_s,wq_c,wk_c,wv_c,wo_s,wo_c}^T [col][k],
//   8..10 = WgT [128 col][384 k]. Blocks 11,12: W2'=(WoS@Wg2)^T, W3'=(WoC@Wg3)^T.
// Block 13: bg' = bg + bos@Wg2 + boc@Wg3.
// ---------------------------------------------------------------------------
__global__ __launch_bounds__(256) void prep_kernel(
    const float* wq_s, const float* wk_s, const float* wv_s,
    const float* wq_c, const float* wk_c, const float* wv_c,
    const float* wo_s, const float* wo_c, const float* wg,
    const float* bos, const float* boc, const float* bgin,
    f16_t* WT, float* bgp)
{
  const int b = blockIdx.x;
  const int tid = threadIdx.x;
  if (b < 11) {
    __shared__ float t[128][129];
    const float* src; f16_t* dst; int ostride;
    switch (b) {
      case 0: src = wq_s; break; case 1: src = wk_s; break;
      case 2: src = wv_s; break; case 3: src = wq_c; break;
      case 4: src = wk_c; break; case 5: src = wv_c; break;
      case 6: src = wo_s; break; case 7: src = wo_c; break;
      default: src = wg + (size_t)(b - 8) * 16384; break;
    }
    if (b < 8) { dst = WT + (size_t)b * 16384; ostride = 128; }
    else       { dst = WT + 8 * 16384 + (b - 8) * 128; ostride = 384; }
#pragma unroll
    for (int i = 0; i < 64; ++i) {
      const int idx = tid + i * 256;
      t[idx & 127][idx >> 7] = src[idx];
    }
    __syncthreads();
#pragma unroll
    for (int i = 0; i < 64; ++i) {
      const int idx = tid + i * 256;
      const int c = idx >> 7, r = idx & 127;
      dst[(size_t)c * ostride + r] = (f16_t)t[c][r];
    }
  } else if (b < 13) {
    const int matsel = b - 11;
    const float* wo = matsel ? wo_c : wo_s;
    const int joff = 128 + matsel * 128;
    f16_t* dst = WT + (size_t)(11 + matsel) * 16384;
    const int wv = tid >> 6, ln = tid & 63, l15 = ln & 15, g = ln >> 4;
    f32x4 acc[2][8];
#pragma unroll
    for (int mm = 0; mm < 2; ++mm)
#pragma unroll
      for (int nt = 0; nt < 8; ++nt) acc[mm][nt] = (f32x4){0.f, 0.f, 0.f, 0.f};
#pragma unroll
    for (int kt = 0; kt < 4; ++kt) {
      f16x8 a[2];
#pragma unroll
      for (int mm = 0; mm < 2; ++mm) {
        const int crow = wv * 32 + mm * 16 + l15;
#pragma unroll
        for (int jj = 0; jj < 8; ++jj)
          a[mm][jj] = (f16_t)wg[(size_t)(joff + kt * 32 + g * 8 + jj) * 128 + crow];
      }
#pragma unroll
      for (int nt = 0; nt < 8; ++nt) {
        f16x8 bf = cvt8(wo + (size_t)(nt * 16 + l15) * 128 + kt * 32 + g * 8);
        acc[0][nt] = __builtin_amdgcn_mfma_f32_16x16x32_f16(a[0], bf, acc[0][nt], 0, 0, 0);
        acc[1][nt] = __builtin_amdgcn_mfma_f32_16x16x32_f16(a[1], bf, acc[1][nt], 0, 0, 0);
      }
    }
#pragma unroll
    for (int mm = 0; mm < 2; ++mm)
#pragma unroll
      for (int nt = 0; nt < 8; ++nt)
#pragma unroll
        for (int r = 0; r < 4; ++r) {
          const int c = wv * 32 + mm * 16 + g * 4 + r;
          dst[(size_t)c * 128 + nt * 16 + l15] = (f16_t)acc[mm][nt][r];
        }
  } else {
    if (tid < 128) {
      float acc = bgin[tid];
      for (int j = 0; j < 128; ++j)
        acc += bos[j] * wg[(size_t)(128 + j) * 128 + tid] +
               boc[j] * wg[(size_t)(256 + j) * 128 + tid];
      bgp[tid] = acc;
    }
  }
}

// ---------------------------------------------------------------------------
// Per-wave GEMM: afr (A-frags, own 16 rows) @ W -> 4 col-tiles (this wave's
// 64-col half) -> LDS row-major swizzled, or transposed ([col][row], for V^T).
// ---------------------------------------------------------------------------
template <bool TRANSP>
__device__ __forceinline__ void gemm4(
    const f16x8 afr[4], const f16_t* __restrict__ W, const float* __restrict__ bias,
    char* Ob, int l15, int g, int rg, int colbase)
{
  f32x4 acc[4];
#pragma unroll
  for (int nt = 0; nt < 4; ++nt) acc[nt] = (f32x4){0.f, 0.f, 0.f, 0.f};
#pragma unroll
  for (int nt = 0; nt < 4; ++nt)
#pragma unroll
    for (int kt = 0; kt < 4; ++kt) {
      f16x8 b = *(const f16x8*)(W + (size_t)(colbase + nt * 16 + l15) * 128 + kt * 32 + g * 8);
      acc[nt] = __builtin_amdgcn_mfma_f32_16x16x32_f16(afr[kt], b, acc[nt], 0, 0, 0);
    }
#pragma unroll
  for (int nt = 0; nt < 4; ++nt) {
    const int col = colbase + nt * 16 + l15;
    const float bv = bias[col];
#pragma unroll
    for (int r = 0; r < 4; ++r) {
      const int row = rg * 16 + g * 4 + r;
      const f16_t v = (f16_t)(acc[nt][r] + bv);
      if (TRANSP)
        *(f16_t*)(Ob + col * 256 + ((row * 2) ^ ((col & 7) << 4))) = v;
      else
        *(f16_t*)(Ob + row * 256 + ((col * 2) ^ ((row & 7) << 4))) = v;
    }
  }
}

// ---------------------------------------------------------------------------
// Q-GEMM producing attention B-fragments in registers via per-wave 2KB LDS
// transpose (in-order per-wave DS + fences). bq[h]: lane l15 = q,
// k (= depth) = g*8+j for g<2, zero for g>=2.
// ---------------------------------------------------------------------------
__device__ __forceinline__ void gemmQ(
    const f16x8 afr[4], const f16_t* __restrict__ W, const float* __restrict__ bias,
    char* scr, int l15, int g, int colbase, f16x8 bq[4])
{
  LFENCE();
  f32x4 acc[4];
#pragma unroll
  for (int nt = 0; nt < 4; ++nt) acc[nt] = (f32x4){0.f, 0.f, 0.f, 0.f};
#pragma unroll
  for (int nt = 0; nt < 4; ++nt)
#pragma unroll
    for (int kt = 0; kt < 4; ++kt) {
      f16x8 b = *(const f16x8*)(W + (size_t)(colbase + nt * 16 + l15) * 128 + kt * 32 + g * 8);
      acc[nt] = __builtin_amdgcn_mfma_f32_16x16x32_f16(afr[kt], b, acc[nt], 0, 0, 0);
    }
#pragma unroll
  for (int nt = 0; nt < 4; ++nt) {
    const int col = colbase + nt * 16 + l15;
    const float bv = bias[col];
    const int dloc = nt * 16 + l15;
#pragma unroll
    for (int r = 0; r < 4; ++r) {
      const int qp = g * 4 + r;
      *(f16_t*)(scr + qp * 128 + ((dloc * 2) ^ ((qp & 7) << 4))) = (f16_t)(acc[nt][r] + bv);
    }
  }
  LFENCE();
#pragma unroll
  for (int h = 0; h < 4; ++h) {
    f16x8 z = {0, 0, 0, 0, 0, 0, 0, 0};
    bq[h] = (g < 2)
      ? *(const f16x8*)(scr + l15 * 128 + (((h * 16 + g * 8) * 2) ^ ((l15 & 7) << 4)))
      : z;
  }
  LFENCE();
}

// ---------------------------------------------------------------------------
// Per-wave attention, CHUNKED: 16 q-rows x 4 heads. Per head, 4x 32-key
// chunks: {2 QK mfma -> exp (unnormalized, SHIFT=4) -> P~ f16 to LDS ->
// 1 PV mfma}. Normalize at the END.
// *** r9/r10 BUG FIXED: psum at lane (l15,g) is the row-sum for q=l15 (QK
// D-layout), but PV output o[r] at that lane is for q=g*4+r (PV D-layout).
// The normalizer must be fetched from lane q=g*4+r: invq = shfl(inv, g*4+r).
// r8 avoided this by normalizing P in-register (q=l15 data, q=l15 inv). ***
// ---------------------------------------------------------------------------
__device__ __forceinline__ void attn_w(
    const char* Kb, const char* Vtb, char* ATTo, char* Pw,
    const f16x8 bq[4], const unsigned aw[4],
    int l15, int g, int rg, int ch)
{
  const f32x4 zero = (f32x4){0.f, 0.f, 0.f, 0.f};
#pragma unroll
  for (int hp = 0; hp < 4; ++hp) {
    const int h = ch * 4 + hp;
    const int d = h * 16 + l15;
    float psum = 0.f;
    f32x4 o = zero;
#pragma unroll
    for (int c = 0; c < 4; ++c) {
      f32x4 st[2];
#pragma unroll
      for (int hf = 0; hf < 2; ++hf) {
        const int krow = (c * 2 + hf) * 16 + l15;
        f16x8 ak = {0, 0, 0, 0, 0, 0, 0, 0};
        if (g < 2)
          ak = *(const f16x8*)(Kb + krow * 256 + (((h * 16 + g * 8) * 2) ^ ((krow & 7) << 4)));
        st[hf] = __builtin_amdgcn_mfma_f32_16x16x32_f16(ak, bq[hp], zero, 0, 0, 0);
      }
#pragma unroll
      for (int hf = 0; hf < 2; ++hf) {
        union { f16_t hh[4]; unsigned long long u; } pk;
#pragma unroll
        for (int r = 0; r < 4; ++r) {
          const int k = (c * 2 + hf) * 16 + g * 4 + r;
          const float e = __expf(st[hf][r] * 0.25f - 4.f);
          const float p = ((aw[k >> 5] >> (k & 31)) & 1u) ? e : 0.f;
          psum += p;   // row-sum contribution for q = l15
          pk.hh[r] = (f16_t)p;
        }
        *(unsigned long long*)(Pw + l15 * 80 + hf * 32 + g * 8) = pk.u;
      }
      LFENCE();
      union { unsigned long long u[2]; f16x8 v; } pa2;
      pa2.u[0] = *(const unsigned long long*)(Pw + l15 * 80 + g * 16);
      pa2.u[1] = *(const unsigned long long*)(Pw + l15 * 80 + g * 16 + 8);
      LFENCE();
      f16x8 vb = *(const f16x8*)(Vtb + d * 256 + (((c * 32 + g * 8) * 2) ^ ((d & 7) << 4)));
      o = __builtin_amdgcn_mfma_f32_16x16x32_f16(pa2.v, vb, o, 0, 0, 0);
    }
    psum += __shfl_xor(psum, 16);
    psum += __shfl_xor(psum, 32);
    const float inv = 1.f / psum;   // normalizer for q = l15 (lanes 0..15 canonical)
#pragma unroll
    for (int r = 0; r < 4; ++r) {
      const float invq = __shfl(inv, g * 4 + r);  // normalizer for q = g*4+r
      const int row = rg * 16 + g * 4 + r;
      *(f16_t*)(ATTo + row * 256 + (((h * 16 + l15) * 2) ^ ((row & 7) << 4))) =
          (f16_t)(o[r] * invq);
    }
  }
}

// ---------------------------------------------------------------------------
// Fused per-batch kernel v5: 1 block = 1 batch, 1024 thr = 16 waves.
// launch_bounds(1024) only (r8's ',4' caused VGPR=64 + spill storm).
// Wave (rg, ch): rows rg*16.., col-half/heads ch. x_cross prefetched ph1->ph3.
// ---------------------------------------------------------------------------
__global__ __launch_bounds__(1024) void fused5_kernel(
    const float* __restrict__ Xs_g, const float* __restrict__ Xc_g,
    const int* __restrict__ adj, const int* __restrict__ mask_s,
    const int* __restrict__ mask_c, const f16_t* __restrict__ WT,
    const float* __restrict__ bq_s, const float* __restrict__ bk_s,
    const float* __restrict__ bv_s, const float* __restrict__ bq_c,
    const float* __restrict__ bk_c, const float* __restrict__ bv_c,
    const float* __restrict__ bos, const float* __restrict__ boc,
    const float* __restrict__ bgp, float* __restrict__ OUT)
{
  __shared__ __align__(16) char Kb[32768];    // K_s -> K_c
  __shared__ __align__(16) char Vtb[32768];   // V_s^T -> V_c^T
  __shared__ __align__(16) char ATTs[32768];  // ph1: 16x2KB Q-transpose scratch; ph2+: att_s
  __shared__ __align__(16) char ATTc[32768];  // ph0: adj bits (2KB); ph4+: att_c
  __shared__ __align__(16) char PR[20480];    // 16 x 1280B P scratch (stride 80)
  __shared__ unsigned mwS[4], mwC[4];

  const int bb = blockIdx.x;
  const int tid = threadIdx.x;
  const int wv = tid >> 6, ln = tid & 63, l15 = ln & 15, g = ln >> 4;
  const int rg = wv & 7, ch = wv >> 3;
  const int colbase = ch * 64;
  const int arow = rg * 16 + l15;

  // ---- ph0: adj bitmask (threads 0..511 -> ATTc[0..2KB)), mask ballots ----
  if (tid < 512) {
    const int r = tid >> 2, w = tid & 3;
    const int4* ap = (const int4*)(adj + (size_t)bb * 16384 + r * 128 + w * 32);
    unsigned bits = 0;
#pragma unroll
    for (int i = 0; i < 8; ++i) {
      int4 a = ap[i];
      bits |= ((a.x != 0 ? 1u : 0u) | (a.y != 0 ? 2u : 0u) |
               (a.z != 0 ? 4u : 0u) | (a.w != 0 ? 8u : 0u)) << (i * 4);
    }
    *(unsigned*)(ATTc + r * 16 + w * 4) = bits;
  }
  if (wv < 2) {
    unsigned long long bm = __ballot(mask_s[bb * 128 + wv * 64 + ln] != 0);
    if (ln == 0) { mwS[wv * 2] = (unsigned)bm; mwS[wv * 2 + 1] = (unsigned)(bm >> 32); }
  } else if (wv < 4) {
    unsigned long long bm = __ballot(mask_c[bb * 128 + (wv - 2) * 64 + ln] != 0);
    if (ln == 0) { mwC[(wv - 2) * 2] = (unsigned)bm; mwC[(wv - 2) * 2 + 1] = (unsigned)(bm >> 32); }
  }

  // ---- ph1: K_s, V_s^T -> LDS; Q_s, Q_c -> B-frag regs; prefetch x_cross ----
  f16x8 bqs[4], bqc[4], afrc[4];
  {
    f16x8 afr[4];
#pragma unroll
    for (int kt = 0; kt < 4; ++kt)
      afr[kt] = cvt8(Xs_g + (size_t)bb * 16384 + arow * 128 + kt * 32 + g * 8);
#pragma unroll
    for (int kt = 0; kt < 4; ++kt)  // prefetch for ph3
      afrc[kt] = cvt8(Xc_g + (size_t)bb * 16384 + arow * 128 + kt * 32 + g * 8);
    gemm4<false>(afr, WT + 1 * 16384, bk_s, Kb, l15, g, rg, colbase);
    gemm4<true >(afr, WT + 2 * 16384, bv_s, Vtb, l15, g, rg, colbase);
    char* scr = ATTs + wv * 2048;
    gemmQ(afr, WT + 0 * 16384, bq_s, scr, l15, g, colbase, bqs);
    gemmQ(afr, WT + 3 * 16384, bq_c, scr, l15, g, colbase, bqc);
  }
  __syncthreads();  // b1

  // ---- ph2: self attention -> ATTs ----
  {
    const uint4 a4 = *(const uint4*)(ATTc + arow * 16);
    unsigned aw[4] = {a4.x & mwS[0], a4.y & mwS[1], a4.z & mwS[2], a4.w & mwS[3]};
    attn_w(Kb, Vtb, ATTs, PR + wv * 1280, bqs, aw, l15, g, rg, ch);
  }
  __syncthreads();  // b2

  // ---- ph3: K_c, V_c^T -> LDS ----
  {
    gemm4<false>(afrc, WT + 4 * 16384, bk_c, Kb, l15, g, rg, colbase);
    gemm4<true >(afrc, WT + 5 * 16384, bv_c, Vtb, l15, g, rg, colbase);
  }
  __syncthreads();  // b3

  // ---- ph4: cross attention -> ATTc ----
  {
    unsigned aw[4] = {mwC[0], mwC[1], mwC[2], mwC[3]};
    attn_w(Kb, Vtb, ATTc, PR + wv * 1280, bqc, aw, l15, g, rg, ch);
  }
  __syncthreads();  // b4

  // ---- ph5: out-proj + precomposed gate + blend -> OUT ----
  {
    const int asw = (arow & 7) << 4;
    f16x8 aS[4], aC[4], aX[4];
#pragma unroll
    for (int kt = 0; kt < 4; ++kt) {
      aS[kt] = *(const f16x8*)(ATTs + arow * 256 + ((kt * 64 + g * 16) ^ asw));
      aC[kt] = *(const f16x8*)(ATTc + arow * 256 + ((kt * 64 + g * 16) ^ asw));
      aX[kt] = cvt8(Xs_g + (size_t)bb * 16384 + arow * 128 + kt * 32 + g * 8);
    }
    const f16_t* WoS = WT + 6 * 16384;
    const f16_t* WoC = WT + 7 * 16384;
    const f16_t* Wg1 = WT + 8 * 16384;   // [col][384], k<128 = X part
    const f16_t* W2p = WT + 11 * 16384;
    const f16_t* W3p = WT + 12 * 16384;
    f32x4 accS[4], accC[4], accG[4];
#pragma unroll
    for (int nt = 0; nt < 4; ++nt) {
      accS[nt] = (f32x4){0.f, 0.f, 0.f, 0.f};
      accC[nt] = (f32x4){0.f, 0.f, 0.f, 0.f};
      accG[nt] = (f32x4){0.f, 0.f, 0.f, 0.f};
    }
#pragma unroll
    for (int nt = 0; nt < 4; ++nt) {
      const size_t col = colbase + nt * 16 + l15;
#pragma unroll
      for (int kt = 0; kt < 4; ++kt) {
        const size_t ko = kt * 32 + g * 8;
        f16x8 bS = *(const f16x8*)(WoS + col * 128 + ko);
        f16x8 bC = *(const f16x8*)(WoC + col * 128 + ko);
        f16x8 bG = *(const f16x8*)(Wg1 + col * 384 + ko);
        f16x8 b2 = *(const f16x8*)(W2p + col * 128 + ko);
        f16x8 b3 = *(const f16x8*)(W3p + col * 128 + ko);
        accS[nt] = __builtin_amdgcn_mfma_f32_16x16x32_f16(aS[kt], bS, accS[nt], 0, 0, 0);
        accC[nt] = __builtin_amdgcn_mfma_f32_16x16x32_f16(aC[kt], bC, accC[nt], 0, 0, 0);
        accG[nt] = __builtin_amdgcn_mfma_f32_16x16x32_f16(aX[kt], bG, accG[nt], 0, 0, 0);
        accG[nt] = __builtin_amdgcn_mfma_f32_16x16x32_f16(aS[kt], b2, accG[nt], 0, 0, 0);
        accG[nt] = __builtin_amdgcn_mfma_f32_16x16x32_f16(aC[kt], b3, accG[nt], 0, 0, 0);
      }
    }
#pragma unroll
    for (int nt = 0; nt < 4; ++nt) {
      const int col = colbase + nt * 16 + l15;
      const float bS = bos[col], bC = boc[col], bG = bgp[col];
#pragma unroll
      for (int r = 0; r < 4; ++r) {
        const int row = rg * 16 + g * 4 + r;
        const float os = accS[nt][r] + bS;
        const float oc = accC[nt][r] + bC;
        const float gv = 1.f / (1.f + __expf(-(accG[nt][r] + bG)));
        OUT[(size_t)bb * 16384 + row * 128 + col] = (1.f - gv) * os + gv * oc;
      }
    }
  }
}

// ---------------------------------------------------------------------------
extern "C" void kernel_launch(void* const* d_in, const int* in_sizes, int n_in,
                              void* d_out, int out_size, void* d_ws, size_t ws_size,
                              hipStream_t stream)
{
  const float* x_self  = (const float*)d_in[0];
  const int*   adj     = (const int*)d_in[1];
  const int*   mask_s  = (const int*)d_in[2];
  const float* x_cross = (const float*)d_in[3];
  const int*   mask_c  = (const int*)d_in[4];
  const float* wq_s = (const float*)d_in[5];
  const float* bq_s = (const float*)d_in[6];
  const float* wk_s = (const float*)d_in[7];
  const float* bk_s = (const float*)d_in[8];
  const float* wv_s = (const float*)d_in[9];
  const float* bv_s = (const float*)d_in[10];
  const float* wo_s = (const float*)d_in[11];
  const float* bo_s = (const float*)d_in[12];
  const float* wq_c = (const float*)d_in[13];
  const float* bq_c = (const float*)d_in[14];
  const float* wk_c = (const float*)d_in[15];
  const float* bk_c = (const float*)d_in[16];
  const float* wv_c = (const float*)d_in[17];
  const float* bv_c = (const float*)d_in[18];
  const float* wo_c = (const float*)d_in[19];
  const float* bo_c = (const float*)d_in[20];
  const float* wg   = (const float*)d_in[21];
  const float* bg   = (const float*)d_in[22];
  float* out = (float*)d_out;

  // ws: 13 f16 weight slots + bg' (f32). ~426 KB.
  f16_t* WT  = (f16_t*)d_ws;
  float* bgp = (float*)(WT + 13 * 16384);

  prep_kernel<<<14, 256, 0, stream>>>(wq_s, wk_s, wv_s, wq_c, wk_c, wv_c,
                                      wo_s, wo_c, wg, bo_s, bo_c, bg, WT, bgp);
  fused5_kernel<<<256, 1024, 0, stream>>>(x_self, x_cross, adj, mask_s, mask_c, WT,
                                          bq_s, bk_s, bv_s, bq_c, bk_c, bv_c,
                                          bo_s, bo_c, bgp, out);
}

// Round 12
// 135.509 us; speedup vs baseline: 1.0688x; 1.0688x over previous
//
#include <hip/hip_runtime.h>
#include <hip/hip_bf16.h>

typedef _Float16 f16_t;
typedef __attribute__((ext_vector_type(8))) _Float16 f16x8;
typedef __attribute__((ext_vector_type(4))) float f32x4;

#define LFENCE() asm volatile("" ::: "memory")

__device__ __forceinline__ f16x8 cvt8(const float* p) {
  float4 v0 = *(const float4*)p;
  float4 v1 = *(const float4*)(p + 4);
  f16x8 a;
  a[0] = (f16_t)v0.x; a[1] = (f16_t)v0.y; a[2] = (f16_t)v0.z; a[3] = (f16_t)v0.w;
  a[4] = (f16_t)v1.x; a[5] = (f16_t)v1.y; a[6] = (f16_t)v1.z; a[7] = (f16_t)v1.w;
  return a;
}

// ---------------------------------------------------------------------------
// prep (verified r6-r11): blocks 0..10 transpose+f16 weights
//   slots 0..7 = {wq_s,wk_s,wv_s,wq_c,wk_c,wv_c,wo_s,wo_c}^T [col][k],
//   8..10 = WgT [128 col][384 k]. Blocks 11,12: W2'=(WoS@Wg2)^T, W3'=(WoC@Wg3)^T.
// Block 13: bg' = bg + bos@Wg2 + boc@Wg3.
// ---------------------------------------------------------------------------
__global__ __launch_bounds__(256) void prep_kernel(
    const float* wq_s, const float* wk_s, const float* wv_s,
    const float* wq_c, const float* wk_c, const float* wv_c,
    const float* wo_s, const float* wo_c, const float* wg,
    const float* bos, const float* boc, const float* bgin,
    f16_t* WT, float* bgp)
{
  const int b = blockIdx.x;
  const int tid = threadIdx.x;
  if (b < 11) {
    __shared__ float t[128][129];
    const float* src; f16_t* dst; int ostride;
    switch (b) {
      case 0: src = wq_s; break; case 1: src = wk_s; break;
      case 2: src = wv_s; break; case 3: src = wq_c; break;
      case 4: src = wk_c; break; case 5: src = wv_c; break;
      case 6: src = wo_s; break; case 7: src = wo_c; break;
      default: src = wg + (size_t)(b - 8) * 16384; break;
    }
    if (b < 8) { dst = WT + (size_t)b * 16384; ostride = 128; }
    else       { dst = WT + 8 * 16384 + (b - 8) * 128; ostride = 384; }
#pragma unroll
    for (int i = 0; i < 64; ++i) {
      const int idx = tid + i * 256;
      t[idx & 127][idx >> 7] = src[idx];
    }
    __syncthreads();
#pragma unroll
    for (int i = 0; i < 64; ++i) {
      const int idx = tid + i * 256;
      const int c = idx >> 7, r = idx & 127;
      dst[(size_t)c * ostride + r] = (f16_t)t[c][r];
    }
  } else if (b < 13) {
    const int matsel = b - 11;
    const float* wo = matsel ? wo_c : wo_s;
    const int joff = 128 + matsel * 128;
    f16_t* dst = WT + (size_t)(11 + matsel) * 16384;
    const int wv = tid >> 6, ln = tid & 63, l15 = ln & 15, g = ln >> 4;
    f32x4 acc[2][8];
#pragma unroll
    for (int mm = 0; mm < 2; ++mm)
#pragma unroll
      for (int nt = 0; nt < 8; ++nt) acc[mm][nt] = (f32x4){0.f, 0.f, 0.f, 0.f};
#pragma unroll
    for (int kt = 0; kt < 4; ++kt) {
      f16x8 a[2];
#pragma unroll
      for (int mm = 0; mm < 2; ++mm) {
        const int crow = wv * 32 + mm * 16 + l15;
#pragma unroll
        for (int jj = 0; jj < 8; ++jj)
          a[mm][jj] = (f16_t)wg[(size_t)(joff + kt * 32 + g * 8 + jj) * 128 + crow];
      }
#pragma unroll
      for (int nt = 0; nt < 8; ++nt) {
        f16x8 bf = cvt8(wo + (size_t)(nt * 16 + l15) * 128 + kt * 32 + g * 8);
        acc[0][nt] = __builtin_amdgcn_mfma_f32_16x16x32_f16(a[0], bf, acc[0][nt], 0, 0, 0);
        acc[1][nt] = __builtin_amdgcn_mfma_f32_16x16x32_f16(a[1], bf, acc[1][nt], 0, 0, 0);
      }
    }
#pragma unroll
    for (int mm = 0; mm < 2; ++mm)
#pragma unroll
      for (int nt = 0; nt < 8; ++nt)
#pragma unroll
        for (int r = 0; r < 4; ++r) {
          const int c = wv * 32 + mm * 16 + g * 4 + r;
          dst[(size_t)c * 128 + nt * 16 + l15] = (f16_t)acc[mm][nt][r];
        }
  } else {
    if (tid < 128) {
      float acc = bgin[tid];
      for (int j = 0; j < 128; ++j)
        acc += bos[j] * wg[(size_t)(128 + j) * 128 + tid] +
               boc[j] * wg[(size_t)(256 + j) * 128 + tid];
      bgp[tid] = acc;
    }
  }
}

// ---------------------------------------------------------------------------
// Full-width per-wave GEMM (nt=8): afr (own 16 rows) @ W -> 128 cols -> LDS,
// row-major swizzled or transposed ([col][row], for V^T). (r7-proven.)
// ---------------------------------------------------------------------------
template <bool TRANSP>
__device__ __forceinline__ void gemm8(
    const f16x8 afr[4], const f16_t* __restrict__ W, const float* __restrict__ bias,
    char* Ob, int l15, int g, int rg)
{
  f32x4 acc[8];
#pragma unroll
  for (int nt = 0; nt < 8; ++nt) acc[nt] = (f32x4){0.f, 0.f, 0.f, 0.f};
#pragma unroll
  for (int nt = 0; nt < 8; ++nt)
#pragma unroll
    for (int kt = 0; kt < 4; ++kt) {
      f16x8 b = *(const f16x8*)(W + (size_t)(nt * 16 + l15) * 128 + kt * 32 + g * 8);
      acc[nt] = __builtin_amdgcn_mfma_f32_16x16x32_f16(afr[kt], b, acc[nt], 0, 0, 0);
    }
#pragma unroll
  for (int nt = 0; nt < 8; ++nt) {
    const int col = nt * 16 + l15;
    const float bv = bias[col];
#pragma unroll
    for (int r = 0; r < 4; ++r) {
      const int row = rg * 16 + g * 4 + r;
      const f16_t v = (f16_t)(acc[nt][r] + bv);
      if (TRANSP)
        *(f16_t*)(Ob + col * 256 + ((row * 2) ^ ((col & 7) << 4))) = v;
      else
        *(f16_t*)(Ob + row * 256 + ((col * 2) ^ ((row & 7) << 4))) = v;
    }
  }
}

// ---------------------------------------------------------------------------
// Q-GEMM -> 8 per-head B-frags in regs, via 2 passes through 2KB wave scratch
// (each pass: 64 cols = 4 heads). r8/r11-proven mapping; LFENCE-ordered.
// bq[h]: lane l15 = q, k = depth g*8+j (g<2), zero for g>=2.
// ---------------------------------------------------------------------------
__device__ __forceinline__ void gemmQ2(
    const f16x8 afr[4], const f16_t* __restrict__ W, const float* __restrict__ bias,
    char* scr, int l15, int g, f16x8 bq[8])
{
#pragma unroll
  for (int p = 0; p < 2; ++p) {
    LFENCE();
    f32x4 acc[4];
#pragma unroll
    for (int nt = 0; nt < 4; ++nt) acc[nt] = (f32x4){0.f, 0.f, 0.f, 0.f};
#pragma unroll
    for (int nt = 0; nt < 4; ++nt)
#pragma unroll
      for (int kt = 0; kt < 4; ++kt) {
        f16x8 b = *(const f16x8*)(W + (size_t)(p * 64 + nt * 16 + l15) * 128 + kt * 32 + g * 8);
        acc[nt] = __builtin_amdgcn_mfma_f32_16x16x32_f16(afr[kt], b, acc[nt], 0, 0, 0);
      }
#pragma unroll
    for (int nt = 0; nt < 4; ++nt) {
      const float bv = bias[p * 64 + nt * 16 + l15];
      const int dloc = nt * 16 + l15;  // 0..63
#pragma unroll
      for (int r = 0; r < 4; ++r) {
        const int qp = g * 4 + r;
        *(f16_t*)(scr + qp * 128 + ((dloc * 2) ^ ((qp & 7) << 4))) = (f16_t)(acc[nt][r] + bv);
      }
    }
    LFENCE();
#pragma unroll
    for (int h = 0; h < 4; ++h) {
      f16x8 z = {0, 0, 0, 0, 0, 0, 0, 0};
      bq[p * 4 + h] = (g < 2)
        ? *(const f16x8*)(scr + l15 * 128 + (((h * 16 + g * 8) * 2) ^ ((l15 & 7) << 4)))
        : z;
    }
  }
  LFENCE();
}

// ---------------------------------------------------------------------------
// Branch attention kernel: grid 512 = (branch, batch); 512 thr = 8 waves;
// LDS exactly 80KB -> 2 blocks/CU (16 waves/CU, independent barriers).
// Wave rg owns q-rows rg*16..+16, all 8 heads. Single __syncthreads.
// Masks: per-wave ballots (regs). adj: per-lane global loads + shfl (regs).
// Attention: r11-proven chunked form (unnormalized P, SHIFT=4, invq shfl).
// Output: normalized f16 direct to global ATT[row][col].
// ---------------------------------------------------------------------------
__global__ __launch_bounds__(512) void battn_kernel(
    const float* __restrict__ Xs, const float* __restrict__ Xc,
    const int* __restrict__ adj, const int* __restrict__ mask_s,
    const int* __restrict__ mask_c, const f16_t* __restrict__ WT,
    const float* __restrict__ bq_s, const float* __restrict__ bk_s,
    const float* __restrict__ bv_s, const float* __restrict__ bq_c,
    const float* __restrict__ bk_c, const float* __restrict__ bv_c,
    f16_t* __restrict__ att_s, f16_t* __restrict__ att_c)
{
  __shared__ __align__(16) char Kb[32768];   // K [128 rows][256B] swizzled
  __shared__ __align__(16) char Vtb[32768];  // V^T [128 d][256B] swizzled
  __shared__ __align__(16) char WS[16384];   // 8 x 2KB wave scratch (Q-transpose / P)

  const bool self = blockIdx.x < 256;
  const int bb = blockIdx.x & 255;
  const int tid = threadIdx.x;
  const int rg = tid >> 6, ln = tid & 63, l15 = ln & 15, g = ln >> 4;
  const int arow = rg * 16 + l15;
  char* scr = WS + rg * 2048;

  const f16_t* WQ = WT + (size_t)(self ? 0 : 3) * 16384;
  const f16_t* WK = WT + (size_t)(self ? 1 : 4) * 16384;
  const f16_t* WV = WT + (size_t)(self ? 2 : 5) * 16384;
  const float* bqv = self ? bq_s : bq_c;
  const float* bkv = self ? bk_s : bk_c;
  const float* bvv = self ? bv_s : bv_c;
  const float* XK  = self ? Xs : Xc;   // K/V A-source
  const int* mask  = self ? mask_s : mask_c;
  f16_t* ATT = self ? att_s : att_c;

  // masks via per-wave ballots (no LDS, no barrier)
  unsigned mw[4];
  {
    unsigned long long m0 = __ballot(mask[bb * 128 + ln] != 0);
    unsigned long long m1 = __ballot(mask[bb * 128 + 64 + ln] != 0);
    mw[0] = (unsigned)m0; mw[1] = (unsigned)(m0 >> 32);
    mw[2] = (unsigned)m1; mw[3] = (unsigned)(m1 >> 32);
  }
  // adj bits -> regs: lane ln holds 32-bit word (w = ln>>4) of row rg*16+(ln&15)
  unsigned aw[4];
  if (self) {
    const int row = rg * 16 + (ln & 15);
    const int w = ln >> 4;
    const int4* ap = (const int4*)(adj + ((size_t)bb * 128 + row) * 128 + w * 32);
    unsigned word = 0;
#pragma unroll
    for (int i = 0; i < 8; ++i) {
      int4 a = ap[i];
      word |= ((a.x != 0 ? 1u : 0u) | (a.y != 0 ? 2u : 0u) |
               (a.z != 0 ? 4u : 0u) | (a.w != 0 ? 8u : 0u)) << (i * 4);
    }
#pragma unroll
    for (int w2 = 0; w2 < 4; ++w2)
      aw[w2] = (unsigned)__shfl((int)word, w2 * 16 + l15) & mw[w2];  // row = l15
  } else {
#pragma unroll
    for (int w2 = 0; w2 < 4; ++w2) aw[w2] = mw[w2];
  }

  // ph1: K -> Kb, V^T -> Vtb, Q -> bq[8] regs
  f16x8 bq[8];
  {
    f16x8 afrK[4];
#pragma unroll
    for (int kt = 0; kt < 4; ++kt)
      afrK[kt] = cvt8(XK + (size_t)bb * 16384 + arow * 128 + kt * 32 + g * 8);
    gemm8<false>(afrK, WK, bkv, Kb, l15, g, rg);
    gemm8<true >(afrK, WV, bvv, Vtb, l15, g, rg);
    f16x8 afrQ[4];
    if (self) {
#pragma unroll
      for (int kt = 0; kt < 4; ++kt) afrQ[kt] = afrK[kt];
    } else {
#pragma unroll
      for (int kt = 0; kt < 4; ++kt)
        afrQ[kt] = cvt8(Xs + (size_t)bb * 16384 + arow * 128 + kt * 32 + g * 8);
    }
    gemmQ2(afrQ, WQ, bqv, scr, l15, g, bq);
  }
  __syncthreads();  // the only block barrier

  // ph2: attention, 8 heads, chunked (r11-proven)
  const f32x4 zero = (f32x4){0.f, 0.f, 0.f, 0.f};
  char* Pw = scr;  // 1280B P region (scr free after gemmQ2; LFENCE-ordered)
#pragma unroll
  for (int h = 0; h < 8; ++h) {
    const int d = h * 16 + l15;
    float psum = 0.f;
    f32x4 o = zero;
#pragma unroll
    for (int c = 0; c < 4; ++c) {
      f32x4 st[2];
#pragma unroll
      for (int hf = 0; hf < 2; ++hf) {
        const int krow = (c * 2 + hf) * 16 + l15;
        f16x8 ak = {0, 0, 0, 0, 0, 0, 0, 0};
        if (g < 2)
          ak = *(const f16x8*)(Kb + krow * 256 + (((h * 16 + g * 8) * 2) ^ ((krow & 7) << 4)));
        st[hf] = __builtin_amdgcn_mfma_f32_16x16x32_f16(ak, bq[h], zero, 0, 0, 0);
      }
#pragma unroll
      for (int hf = 0; hf < 2; ++hf) {
        union { f16_t hh[4]; unsigned long long u; } pk;
#pragma unroll
        for (int r = 0; r < 4; ++r) {
          const int k = (c * 2 + hf) * 16 + g * 4 + r;
          const float e = __expf(st[hf][r] * 0.25f - 4.f);
          const float p = ((aw[k >> 5] >> (k & 31)) & 1u) ? e : 0.f;
          psum += p;   // row-sum for q = l15
          pk.hh[r] = (f16_t)p;
        }
        *(unsigned long long*)(Pw + l15 * 80 + hf * 32 + g * 8) = pk.u;
      }
      LFENCE();
      union { unsigned long long u[2]; f16x8 v; } pa2;
      pa2.u[0] = *(const unsigned long long*)(Pw + l15 * 80 + g * 16);
      pa2.u[1] = *(const unsigned long long*)(Pw + l15 * 80 + g * 16 + 8);
      LFENCE();
      f16x8 vb = *(const f16x8*)(Vtb + d * 256 + (((c * 32 + g * 8) * 2) ^ ((d & 7) << 4)));
      o = __builtin_amdgcn_mfma_f32_16x16x32_f16(pa2.v, vb, o, 0, 0, 0);
    }
    psum += __shfl_xor(psum, 16);
    psum += __shfl_xor(psum, 32);
    const float inv = 1.f / psum;  // for q = l15
#pragma unroll
    for (int r = 0; r < 4; ++r) {
      const float invq = __shfl(inv, g * 4 + r);  // for q = g*4+r (PV D-layout)
      const int row = rg * 16 + g * 4 + r;
      ATT[(size_t)bb * 16384 + row * 128 + h * 16 + l15] = (f16_t)(o[r] * invq);
    }
  }
}

// ---------------------------------------------------------------------------
// outgate2 (verbatim from passing r6): straight-line out-proj + precomposed
// gate + blend. Grid 1024 x 256 thr; wave = 16 rows x 64 cols; no LDS.
// ---------------------------------------------------------------------------
__global__ __launch_bounds__(256) void outgate2_kernel(
    const f16_t* __restrict__ AS, const f16_t* __restrict__ AC,
    const float* __restrict__ X, const f16_t* __restrict__ WT,
    const float* __restrict__ bos, const float* __restrict__ boc,
    const float* __restrict__ bgp, float* __restrict__ OUT)
{
  const int tid = threadIdx.x;
  const int wv = tid >> 6, ln = tid & 63, l15 = ln & 15, g = ln >> 4;
  const int rowgrp = wv & 1, colgrp = wv >> 1;
  const size_t arow = (size_t)blockIdx.x * 32 + rowgrp * 16 + l15;
  const f16_t* WoS = WT + 6 * 16384;
  const f16_t* WoC = WT + 7 * 16384;
  const f16_t* WgT = WT + 8 * 16384;   // [128][384]; k<128 = X part
  const f16_t* W2T = WT + 11 * 16384;
  const f16_t* W3T = WT + 12 * 16384;

  f32x4 accS[4], accC[4], accG[4];
#pragma unroll
  for (int nt = 0; nt < 4; ++nt) {
    accS[nt] = (f32x4){0.f, 0.f, 0.f, 0.f};
    accC[nt] = (f32x4){0.f, 0.f, 0.f, 0.f};
    accG[nt] = (f32x4){0.f, 0.f, 0.f, 0.f};
  }

#pragma unroll
  for (int kt = 0; kt < 4; ++kt) {
    const size_t ko = kt * 32 + g * 8;
    f16x8 aS = *(const f16x8*)(AS + arow * 128 + ko);
    f16x8 aC = *(const f16x8*)(AC + arow * 128 + ko);
    f16x8 aX = cvt8(X + arow * 128 + ko);
#pragma unroll
    for (int nt = 0; nt < 4; ++nt) {
      const size_t col = colgrp * 64 + nt * 16 + l15;
      f16x8 bS = *(const f16x8*)(WoS + col * 128 + ko);
      f16x8 bC = *(const f16x8*)(WoC + col * 128 + ko);
      f16x8 b2 = *(const f16x8*)(W2T + col * 128 + ko);
      f16x8 b3 = *(const f16x8*)(W3T + col * 128 + ko);
      f16x8 bX = *(const f16x8*)(WgT + col * 384 + ko);
      accS[nt] = __builtin_amdgcn_mfma_f32_16x16x32_f16(aS, bS, accS[nt], 0, 0, 0);
      accC[nt] = __builtin_amdgcn_mfma_f32_16x16x32_f16(aC, bC, accC[nt], 0, 0, 0);
      accG[nt] = __builtin_amdgcn_mfma_f32_16x16x32_f16(aX, bX, accG[nt], 0, 0, 0);
      accG[nt] = __builtin_amdgcn_mfma_f32_16x16x32_f16(aS, b2, accG[nt], 0, 0, 0);
      accG[nt] = __builtin_amdgcn_mfma_f32_16x16x32_f16(aC, b3, accG[nt], 0, 0, 0);
    }
  }

  const size_t orow0 = (size_t)blockIdx.x * 32 + rowgrp * 16 + g * 4;
#pragma unroll
  for (int nt = 0; nt < 4; ++nt) {
    const int col = colgrp * 64 + nt * 16 + l15;
    const float bS = bos[col], bC = boc[col], bG = bgp[col];
#pragma unroll
    for (int r = 0; r < 4; ++r) {
      const float os = accS[nt][r] + bS;
      const float oc = accC[nt][r] + bC;
      const float gv = 1.f / (1.f + __expf(-(accG[nt][r] + bG)));
      OUT[(orow0 + r) * 128 + col] = (1.f - gv) * os + gv * oc;
    }
  }
}

// ---------------------------------------------------------------------------
extern "C" void kernel_launch(void* const* d_in, const int* in_sizes, int n_in,
                              void* d_out, int out_size, void* d_ws, size_t ws_size,
                              hipStream_t stream)
{
  const float* x_self  = (const float*)d_in[0];
  const int*   adj     = (const int*)d_in[1];
  const int*   mask_s  = (const int*)d_in[2];
  const float* x_cross = (const float*)d_in[3];
  const int*   mask_c  = (const int*)d_in[4];
  const float* wq_s = (const float*)d_in[5];
  const float* bq_s = (const float*)d_in[6];
  const float* wk_s = (const float*)d_in[7];
  const float* bk_s = (const float*)d_in[8];
  const float* wv_s = (const float*)d_in[9];
  const float* bv_s = (const float*)d_in[10];
  const float* wo_s = (const float*)d_in[11];
  const float* bo_s = (const float*)d_in[12];
  const float* wq_c = (const float*)d_in[13];
  const float* bq_c = (const float*)d_in[14];
  const float* wk_c = (const float*)d_in[15];
  const float* bk_c = (const float*)d_in[16];
  const float* wv_c = (const float*)d_in[17];
  const float* bv_c = (const float*)d_in[18];
  const float* wo_c = (const float*)d_in[19];
  const float* bo_c = (const float*)d_in[20];
  const float* wg   = (const float*)d_in[21];
  const float* bg   = (const float*)d_in[22];
  float* out = (float*)d_out;

  // ws: 13 f16 weight slots + bg' (f32) + att_s/att_c (f16, 8.4MB each). ~17.2MB.
  const size_t SZ = (size_t)256 * 128 * 128;
  f16_t* WT  = (f16_t*)d_ws;
  float* bgp = (float*)(WT + 13 * 16384);
  f16_t* att_s = (f16_t*)(bgp + 128);
  f16_t* att_c = att_s + SZ;

  prep_kernel<<<14, 256, 0, stream>>>(wq_s, wk_s, wv_s, wq_c, wk_c, wv_c,
                                      wo_s, wo_c, wg, bo_s, bo_c, bg, WT, bgp);
  battn_kernel<<<512, 512, 0, stream>>>(x_self, x_cross, adj, mask_s, mask_c, WT,
                                        bq_s, bk_s, bv_s, bq_c, bk_c, bv_c,
                                        att_s, att_c);
  outgate2_kernel<<<1024, 256, 0, stream>>>(att_s, att_c, x_self, WT,
                                            bo_s, bo_c, bgp, out);
}